// Round 1
// baseline (1377.015 us; speedup 1.0000x reference)
//
#include <hip/hip_runtime.h>
#include <hip/hip_fp16.h>

// Sinkhorn-Knopp, factorized: M = exp(H) * diag-row(r) * diag-col(c).
// Only r (64x1024) and c (64x1024) evolve across the 20 iterations; the
// 256MB matrix is read (as fp16, 128MB) once per half-iteration for a
// matvec, and written once at the end.

constexpr int NBATCH = 64;
constexpr int N      = 1024;
constexpr int SLABS  = 8;            // row slabs per batch
constexpr int ROWS   = N / SLABS;    // 128 rows per slab
constexpr int NITER  = 20;
constexpr float EPS  = 1e-8f;

// ---- vector load/store helpers (fp16 or fp32 storage of E) ----
__device__ inline float4 load4(const __half* p) {
  uint2 u = *reinterpret_cast<const uint2*>(p);
  __half2 h0 = *reinterpret_cast<__half2*>(&u.x);
  __half2 h1 = *reinterpret_cast<__half2*>(&u.y);
  float2 f0 = __half22float2(h0), f1 = __half22float2(h1);
  return make_float4(f0.x, f0.y, f1.x, f1.y);
}
__device__ inline float4 load4(const float* p) {
  return *reinterpret_cast<const float4*>(p);
}
__device__ inline void store4(__half* p, float4 v) {
  __half2 h0 = __floats2half2_rn(v.x, v.y);
  __half2 h1 = __floats2half2_rn(v.z, v.w);
  uint2 u;
  u.x = *reinterpret_cast<unsigned int*>(&h0);
  u.y = *reinterpret_cast<unsigned int*>(&h1);
  *reinterpret_cast<uint2*>(p) = u;
}
__device__ inline void store4(float* p, float4 v) {
  *reinterpret_cast<float4*>(p) = v;
}

// ---- E = exp(H) ----
template <typename ET>
__global__ void k_init(const float* __restrict__ H, ET* __restrict__ E) {
  size_t idx = ((size_t)blockIdx.x * 256 + threadIdx.x) * 4;
  float4 h = *reinterpret_cast<const float4*>(H + idx);
  float4 e = make_float4(__expf(h.x), __expf(h.y), __expf(h.z), __expf(h.w));
  store4(E + idx, e);
}

// ---- column phase: fold in r update, emit per-slab column partials ----
// Apart[b][s][j] = sum_{i in slab s} E[b][i][j] * r_new[b][i]
template <typename ET>
__global__ void k_col(const ET* __restrict__ E, const float* __restrict__ rR,
                      const float* __restrict__ Bv, float* __restrict__ rW,
                      float* __restrict__ Apart, int first) {
  int b = blockIdx.x / SLABS, s = blockIdx.x % SLABS;
  int tid = threadIdx.x;
  __shared__ float rs[ROWS];
  int i0 = s * ROWS;
  if (tid < ROWS) {
    float rn;
    if (first) {
      rn = 1.0f;
    } else {
      float rv = rR[b * N + i0 + tid];
      float bv = Bv[b * N + i0 + tid];
      rn = rv / (rv * bv + EPS);
    }
    rs[tid] = rn;
    rW[b * N + i0 + tid] = rn;
  }
  __syncthreads();
  float a0 = 0.f, a1 = 0.f, a2 = 0.f, a3 = 0.f;
  const ET* Eb = E + ((size_t)b * N + i0) * N + tid * 4;
#pragma unroll 4
  for (int i = 0; i < ROWS; i++) {
    float rv = rs[i];
    float4 e = load4(Eb + (size_t)i * N);
    a0 += e.x * rv; a1 += e.y * rv; a2 += e.z * rv; a3 += e.w * rv;
  }
  store4(Apart + ((size_t)(b * SLABS + s)) * N + tid * 4,
         make_float4(a0, a1, a2, a3));
}

// ---- row phase: fold in c update (redundant per block), emit row sums ----
// Bv[b][i] = sum_j E[b][i][j] * c_new[b][j]
template <typename ET>
__global__ void k_row(const ET* __restrict__ E, const float* __restrict__ cR,
                      const float* __restrict__ Apart, float* __restrict__ cW,
                      float* __restrict__ Bv, int first) {
  int b = blockIdx.x / SLABS, s = blockIdx.x % SLABS;
  int tid = threadIdx.x;
  __shared__ float cs[N];
#pragma unroll
  for (int q = 0; q < 4; q++) {
    int j = tid + q * 256;
    float A = 0.f;
#pragma unroll
    for (int p = 0; p < SLABS; p++) A += Apart[((size_t)(b * SLABS + p)) * N + j];
    float cn;
    if (first) {
      cn = 1.0f / (A + EPS);
    } else {
      float cv = cR[b * N + j];
      cn = cv / (cv * A + EPS);
    }
    cs[j] = cn;
    if (s == 0) cW[b * N + j] = cn;  // materialize for next iteration / output
  }
  __syncthreads();
  int wave = tid >> 6, lane = tid & 63;
  float c_reg[16];
#pragma unroll
  for (int q = 0; q < 4; q++)
#pragma unroll
    for (int m = 0; m < 4; m++) c_reg[q * 4 + m] = cs[q * 256 + lane * 4 + m];
  int i0 = s * ROWS;
  for (int ii = wave; ii < ROWS; ii += 4) {
    int i = i0 + ii;
    const ET* Er = E + ((size_t)b * N + i) * N;
    float acc = 0.f;
#pragma unroll
    for (int q = 0; q < 4; q++) {
      float4 e = load4(Er + q * 256 + lane * 4);
      acc += e.x * c_reg[4 * q + 0] + e.y * c_reg[4 * q + 1] +
             e.z * c_reg[4 * q + 2] + e.w * c_reg[4 * q + 3];
    }
#pragma unroll
    for (int off = 32; off; off >>= 1) acc += __shfl_xor(acc, off, 64);
    if (lane == 0) Bv[b * N + i] = acc;
  }
}

// ---- output: M = E * r_final * c_final (r_final folded in lazily) ----
// NOTE: no __restrict__ on E/M — fallback path aliases them (in-place).
template <typename ET>
__global__ void k_out(const ET* E, const float* __restrict__ rR,
                      const float* __restrict__ Bv, const float* __restrict__ cR,
                      float* M) {
  int b = blockIdx.x / SLABS, s = blockIdx.x % SLABS;
  int tid = threadIdx.x;
  __shared__ float rs[ROWS];
  int i0 = s * ROWS;
  if (tid < ROWS) {
    float rv = rR[b * N + i0 + tid];
    float bv = Bv[b * N + i0 + tid];
    rs[tid] = rv / (rv * bv + EPS);
  }
  __syncthreads();
  float4 c4 = *reinterpret_cast<const float4*>(cR + b * N + tid * 4);
  const ET* Eb = E + ((size_t)b * N + i0) * N + tid * 4;
  float* Mb = M + ((size_t)b * N + i0) * N + tid * 4;
  for (int i = 0; i < ROWS; i++) {
    float rv = rs[i];
    float4 e = load4(Eb + (size_t)i * N);
    float4 o = make_float4(e.x * rv * c4.x, e.y * rv * c4.y,
                           e.z * rv * c4.z, e.w * rv * c4.w);
    store4(Mb + (size_t)i * N, o);
  }
}

template <typename ET>
static void run_pipeline(const float* H, ET* E, float* fbase, float* M,
                         hipStream_t stream) {
  float* r0 = fbase;
  float* r1 = fbase + 65536;
  float* c0 = fbase + 2 * 65536;
  float* c1 = fbase + 3 * 65536;
  float* Bv = fbase + 4 * 65536;
  float* Ap = fbase + 5 * 65536;  // 64*8*1024 floats
  float* rb[2] = {r0, r1};
  float* cb[2] = {c0, c1};
  const size_t nElem = (size_t)NBATCH * N * N;

  k_init<ET><<<dim3((unsigned)(nElem / 1024)), dim3(256), 0, stream>>>(H, E);
  for (int k0 = 0; k0 < NITER; k0++) {
    int first = (k0 == 0) ? 1 : 0;
    // k = k0+1: writes r_{k-1} to rb[(k-1)%2]=rb[k0%2], reads r_{k-2}=rb[(k0+1)%2]
    k_col<ET><<<dim3(NBATCH * SLABS), dim3(256), 0, stream>>>(
        E, rb[(k0 + 1) & 1], Bv, rb[k0 & 1], Ap, first);
    // writes c_k to cb[k%2]=cb[(k0+1)%2], reads c_{k-1}=cb[k0%2]
    k_row<ET><<<dim3(NBATCH * SLABS), dim3(256), 0, stream>>>(
        E, cb[k0 & 1], Ap, cb[(k0 + 1) & 1], Bv, first);
  }
  // c_20 = cb[20%2] = cb[0]; r_19 = rb[19%2] = rb[1]; B_20 = Bv
  k_out<ET><<<dim3(NBATCH * SLABS), dim3(256), 0, stream>>>(E, rb[1], Bv, cb[0], M);
}

extern "C" void kernel_launch(void* const* d_in, const int* in_sizes, int n_in,
                              void* d_out, int out_size, void* d_ws, size_t ws_size,
                              hipStream_t stream) {
  const float* H = (const float*)d_in[0];
  float* M = (float*)d_out;
  const size_t nElem = (size_t)NBATCH * N * N;        // 67,108,864
  const size_t smallFloats = 5 * 65536 + (size_t)NBATCH * SLABS * N;
  const size_t smallBytes = smallFloats * sizeof(float);   // ~3.4 MB
  const size_t halfBytes = nElem * sizeof(__half);         // 128 MB

  if (ws_size >= halfBytes + smallBytes) {
    // Fast path: fp16 E in workspace (fits Infinity Cache).
    __half* E = (__half*)d_ws;
    float* fbase = (float*)((char*)d_ws + halfBytes);
    run_pipeline<__half>(H, E, fbase, M, stream);
  } else {
    // Fallback: fp32 E lives in d_out, scaled in place at the end.
    float* E = M;
    float* fbase = (float*)d_ws;
    run_pipeline<float>(H, E, fbase, M, stream);
  }
}

// Round 2
// 1069.752 us; speedup vs baseline: 1.2872x; 1.2872x over previous
//
#include <hip/hip_runtime.h>
#include <hip/hip_fp16.h>

// Sinkhorn-Knopp, factorized M = diag(r) * exp(H) * diag(c).
// One fused pass per iteration:
//   phase a: c_new from previous pass's column partials (redundant per block)
//   phase b: per row: B_i = E_row . c_new  ->  r_new_i  -> accumulate
//            next iteration's column partials from the SAME registers.
// Pass 20 writes M = r*E*c directly instead of partials.
// E stored fp16 (128 MB -> Infinity-Cache resident across the 20 passes).

constexpr int NB    = 64;
constexpr int N     = 1024;
constexpr int SLABS = 8;            // blocks per batch
constexpr int TPB   = 512;          // threads per block (8 waves)
constexpr int WAVES = TPB / 64;     // 8
constexpr int RPB   = N / SLABS;    // 128 rows per block
constexpr int RPW   = RPB / WAVES;  // 16 rows per wave
constexpr int NITER = 20;
constexpr float EPS = 1e-8f;

template <typename ET> struct VT;
template <> struct VT<__half> { static constexpr int CPL = 8, STEPS = 2; };
template <> struct VT<float>  { static constexpr int CPL = 4, STEPS = 4; };

// 16 B load -> CPL floats
__device__ inline void load16B(const __half* p, float* f) {
  uint4 u = *reinterpret_cast<const uint4*>(p);
  float2 t;
  t = __half22float2(*reinterpret_cast<__half2*>(&u.x)); f[0] = t.x; f[1] = t.y;
  t = __half22float2(*reinterpret_cast<__half2*>(&u.y)); f[2] = t.x; f[3] = t.y;
  t = __half22float2(*reinterpret_cast<__half2*>(&u.z)); f[4] = t.x; f[5] = t.y;
  t = __half22float2(*reinterpret_cast<__half2*>(&u.w)); f[6] = t.x; f[7] = t.y;
}
__device__ inline void load16B(const float* p, float* f) {
  float4 v = *reinterpret_cast<const float4*>(p);
  f[0] = v.x; f[1] = v.y; f[2] = v.z; f[3] = v.w;
}

// ---- init: E = exp(H), plus iteration-1 column partials (r = 1) ----
template <typename ET>
__global__ __launch_bounds__(TPB, 4) void k_init(const float* __restrict__ H,
                                                 ET* __restrict__ E,
                                                 float* __restrict__ Apart0) {
  __shared__ float red[WAVES][N];
  int b = blockIdx.x / SLABS, s = blockIdx.x % SLABS;
  int tid = threadIdx.x, w = tid >> 6, l = tid & 63;
  float ca[16];
#pragma unroll
  for (int k = 0; k < 16; ++k) ca[k] = 0.f;
  int i0 = s * RPB + w * RPW;
  for (int t = 0; t < RPW; ++t) {
    size_t rowoff = ((size_t)b * N + (i0 + t)) * N;
    const float* Hrow = H + rowoff;
#pragma unroll
    for (int q = 0; q < 4; ++q) {
      int c0 = q * 256 + l * 4;
      float4 h = *reinterpret_cast<const float4*>(Hrow + c0);
      float e0 = __expf(h.x), e1 = __expf(h.y), e2 = __expf(h.z), e3 = __expf(h.w);
      if constexpr (sizeof(ET) == 2) {
        __half2 p0 = __floats2half2_rn(e0, e1);
        __half2 p1 = __floats2half2_rn(e2, e3);
        uint2 u;
        u.x = *reinterpret_cast<unsigned*>(&p0);
        u.y = *reinterpret_cast<unsigned*>(&p1);
        *reinterpret_cast<uint2*>((__half*)(E + rowoff) + c0) = u;
        // accumulate the ROUNDED values so partials match stored E
        float2 r0 = __half22float2(p0), r1 = __half22float2(p1);
        ca[q * 4 + 0] += r0.x; ca[q * 4 + 1] += r0.y;
        ca[q * 4 + 2] += r1.x; ca[q * 4 + 3] += r1.y;
      } else {
        *reinterpret_cast<float4*>((float*)(E + rowoff) + c0) =
            make_float4(e0, e1, e2, e3);
        ca[q * 4 + 0] += e0; ca[q * 4 + 1] += e1;
        ca[q * 4 + 2] += e2; ca[q * 4 + 3] += e3;
      }
    }
  }
#pragma unroll
  for (int q = 0; q < 4; ++q)
    *reinterpret_cast<float4*>(&red[w][q * 256 + l * 4]) =
        make_float4(ca[q * 4], ca[q * 4 + 1], ca[q * 4 + 2], ca[q * 4 + 3]);
  __syncthreads();
  for (int j = tid; j < N; j += TPB) {
    float a = 0.f;
#pragma unroll
    for (int p = 0; p < WAVES; ++p) a += red[p][j];
    Apart0[((size_t)b * SLABS + s) * N + j] = a;
  }
}

// ---- one Sinkhorn iteration per launch ----
// NOTE: E and M deliberately NOT both __restrict__ — fp32 fallback aliases them.
template <typename ET, bool FIRST, bool LAST>
__global__ __launch_bounds__(TPB, 4) void k_pass(
    const ET* E, const float* __restrict__ ApartIn, float* __restrict__ ApartOut,
    const float* __restrict__ cIn, float* __restrict__ cOut,
    float* __restrict__ rbuf, float* M) {
  constexpr int CPL = VT<ET>::CPL, ST = VT<ET>::STEPS;
  __shared__ float cs[N];
  __shared__ float red[WAVES][N];
  int b = blockIdx.x / SLABS, s = blockIdx.x % SLABS;
  int tid = threadIdx.x, w = tid >> 6, l = tid & 63;

  // phase a: column-scale update from previous pass's partials
  for (int j = tid; j < N; j += TPB) {
    float A = 0.f;
#pragma unroll
    for (int p = 0; p < SLABS; ++p)
      A += ApartIn[((size_t)b * SLABS + p) * N + j];
    float cn;
    if (FIRST) {
      cn = 1.f / (A + EPS);
    } else {
      float cv = cIn[(size_t)b * N + j];
      cn = cv / (cv * A + EPS);
    }
    cs[j] = cn;
    if (!LAST && s == 0) cOut[(size_t)b * N + j] = cn;
  }
  __syncthreads();

  float creg[ST * CPL];
#pragma unroll
  for (int q = 0; q < ST; ++q)
#pragma unroll
    for (int m = 0; m < CPL; ++m)
      creg[q * CPL + m] = cs[q * (64 * CPL) + l * CPL + m];

  float ca[ST * CPL];
#pragma unroll
  for (int k = 0; k < ST * CPL; ++k) ca[k] = 0.f;

  int i0 = s * RPB + w * RPW;
#pragma unroll 2
  for (int t = 0; t < RPW; ++t) {
    int i = i0 + t;
    size_t rowoff = ((size_t)b * N + i) * N;
    const ET* Erow = E + rowoff;
    float ev[ST * CPL];
#pragma unroll
    for (int q = 0; q < ST; ++q)
      load16B(Erow + q * (64 * CPL) + l * CPL, &ev[q * CPL]);
    // row sum with new c
    float acc = 0.f;
#pragma unroll
    for (int k = 0; k < ST * CPL; ++k) acc = fmaf(ev[k], creg[k], acc);
#pragma unroll
    for (int off = 32; off > 0; off >>= 1) acc += __shfl_xor(acc, off, 64);
    // row-scale update (row-local!)
    float ro = FIRST ? 1.f : rbuf[(size_t)b * N + i];
    float rn = ro / (ro * acc + EPS);
    if (LAST) {
      float* Mrow = M + rowoff;
#pragma unroll
      for (int q = 0; q < ST; ++q)
#pragma unroll
        for (int v = 0; v < CPL / 4; ++v) {
          int k = q * CPL + v * 4;
          float4 o = make_float4(ev[k] * rn * creg[k],
                                 ev[k + 1] * rn * creg[k + 1],
                                 ev[k + 2] * rn * creg[k + 2],
                                 ev[k + 3] * rn * creg[k + 3]);
          *reinterpret_cast<float4*>(Mrow + q * (64 * CPL) + l * CPL + v * 4) = o;
        }
    } else {
      if (l == 0) rbuf[(size_t)b * N + i] = rn;
      // next iteration's column partials from the SAME registers
#pragma unroll
      for (int k = 0; k < ST * CPL; ++k) ca[k] = fmaf(ev[k], rn, ca[k]);
    }
  }

  if (!LAST) {
#pragma unroll
    for (int q = 0; q < ST; ++q)
#pragma unroll
      for (int v = 0; v < CPL / 4; ++v) {
        int k = q * CPL + v * 4;
        *reinterpret_cast<float4*>(&red[w][q * (64 * CPL) + l * CPL + v * 4]) =
            make_float4(ca[k], ca[k + 1], ca[k + 2], ca[k + 3]);
      }
    __syncthreads();
    for (int j = tid; j < N; j += TPB) {
      float a = 0.f;
#pragma unroll
      for (int p = 0; p < WAVES; ++p) a += red[p][j];
      ApartOut[((size_t)b * SLABS + s) * N + j] = a;
    }
  }
}

template <typename ET>
static void run(const float* H, ET* E, float* base, float* M, hipStream_t st) {
  float* Ap[2] = {base, base + (size_t)NB * SLABS * N};
  float* c0 = base + 2 * (size_t)NB * SLABS * N;
  float* cb[2] = {c0, c0 + (size_t)NB * N};
  float* r = c0 + 2 * (size_t)NB * N;
  dim3 g(NB * SLABS), blk(TPB);
  k_init<ET><<<g, blk, 0, st>>>(H, E, Ap[0]);
  for (int j = 0; j < NITER; ++j) {
    const float* ApI = Ap[j & 1];
    float* ApO = Ap[(j + 1) & 1];
    const float* cI = cb[j & 1];
    float* cO = cb[(j + 1) & 1];
    if (j == 0)
      k_pass<ET, true, false><<<g, blk, 0, st>>>(E, ApI, ApO, cI, cO, r, M);
    else if (j == NITER - 1)
      k_pass<ET, false, true><<<g, blk, 0, st>>>(E, ApI, ApO, cI, cO, r, M);
    else
      k_pass<ET, false, false><<<g, blk, 0, st>>>(E, ApI, ApO, cI, cO, r, M);
  }
}

extern "C" void kernel_launch(void* const* d_in, const int* in_sizes, int n_in,
                              void* d_out, int out_size, void* d_ws, size_t ws_size,
                              hipStream_t stream) {
  const float* H = (const float*)d_in[0];
  float* M = (float*)d_out;
  const size_t smallFloats = 2 * (size_t)NB * SLABS * N + 3 * (size_t)NB * N;
  const size_t eBytes = (size_t)NB * N * N * sizeof(__half);  // 128 MB
  if (ws_size >= eBytes + smallFloats * sizeof(float)) {
    // fast path: fp16 E in workspace (L3-resident across passes)
    run<__half>(H, (__half*)d_ws, (float*)((char*)d_ws + eBytes), M, stream);
  } else {
    // fallback: fp32 E aliased with the output buffer, scaled in place on pass 20
    run<float>(H, M, (float*)d_ws, M, stream);
  }
}